// Round 4
// baseline (888.229 us; speedup 1.0000x reference)
//
#include <hip/hip_runtime.h>
#include <stdint.h>
#include <math.h>

#define N_ANCH   1000000
#define PRE_K    6000
#define POST_K   1000
#define WORDS    94            // ceil(6000/64) -> 6016 bit columns
#define ROWS     6016          // WORDS*64
#define W_IMG    1333.0f
#define H_IMG    800.0f
#define NBLK1    64            // histogram blocks (x1024 threads)

// radix sort config (single block)
#define NS       7168          // sort capacity (112 tiles of 64)
#define TILES    112
#define TPW      7             // tiles per wave (16 waves)
#define PASSES   13            // 13 x 4 bits = 52 = 32-bit key + 20-bit idx

// ws layout (bytes)
#define OFF_KEYS   0x000000u   // u32[1e6]
#define OFF_PART1  0x400000u   // u32[NBLK1*4096] = 1 MiB
#define OFF_PART2  0x500000u   // u32[NBLK1*256]  = 64 KiB
#define OFF_CTRL   0x510000u   // [0]=count [1]=T20 [2]=coarse c [3]=base [4],[5]=done ctrs
#define OFF_CAND   0x510100u   // u64[NS] 56 KiB
#define OFF_BOXES  0x51F000u   // float4[6016]
#define OFF_VALID  0x537000u   // u32[6016]
#define OFF_MASK   0x540000u   // u64[6016*94] row-major: mask[row*WORDS + w]

__device__ __forceinline__ float ref_exp(float v) {
  return (float)exp((double)v);   // correctly-rounded f32 exp via double
}

__device__ __forceinline__ void decode_box(float ax, float ay, float az, float aw,
                                           float dx, float dy, float dz, float dw,
                                           float& x1, float& y1, float& x2, float& y2,
                                           bool& valid) {
  // bit-exact replica of reference fp32 op order (no FMA contraction)
  float wa = __fsub_rn(az, ax);
  float ha = __fsub_rn(aw, ay);
  float xa = __fadd_rn(ax, __fmul_rn(0.5f, wa));
  float ya = __fadd_rn(ay, __fmul_rn(0.5f, ha));
  float x  = __fadd_rn(__fmul_rn(dx, wa), xa);
  float y  = __fadd_rn(__fmul_rn(dy, ha), ya);
  float w  = __fmul_rn(ref_exp(dz), wa);
  float h  = __fmul_rn(ref_exp(dw), ha);
  float hw = __fmul_rn(0.5f, w);
  float hh = __fmul_rn(0.5f, h);
  x1 = fminf(fmaxf(__fsub_rn(x, hw), 0.0f), W_IMG - 1.0f);
  y1 = fminf(fmaxf(__fsub_rn(y, hh), 0.0f), H_IMG - 1.0f);
  x2 = fminf(fmaxf(__fadd_rn(x, hw), 0.0f), W_IMG - 1.0f);
  y2 = fminf(fmaxf(__fadd_rn(y, hh), 0.0f), H_IMG - 1.0f);
  valid = (__fsub_rn(x2, x1) >= 16.0f) && (__fsub_rn(y2, y1) >= 16.0f);
}

__device__ __forceinline__ uint32_t wave_iscan(uint32_t x, int lane) {
  #pragma unroll
  for (int off = 1; off < 64; off <<= 1) {
    uint32_t u = __shfl_up(x, off, 64);
    if (lane >= off) x += u;
  }
  return x;
}

// ---- K1: decode + score key + 12-bit LDS histogram; last block finds coarse cut ----
__global__ void __launch_bounds__(1024) k_score(const float4* __restrict__ anchors,
                                                const float4* __restrict__ deltas,
                                                const float*  __restrict__ logits,
                                                uint32_t* __restrict__ keys,
                                                uint32_t* __restrict__ part1,
                                                uint32_t* __restrict__ ctrl) {
  __shared__ uint32_t lh[4096];
  __shared__ uint32_t amLast;
  int tid = threadIdx.x;
  for (int b = tid; b < 4096; b += 1024) lh[b] = 0u;
  __syncthreads();
  for (int i = blockIdx.x * 1024 + tid; i < N_ANCH; i += NBLK1 * 1024) {
    float4 a = anchors[i];
    float4 d = deltas[i];
    float x1, y1, x2, y2; bool valid;
    decode_box(a.x, a.y, a.z, a.w, d.x, d.y, d.z, d.w, x1, y1, x2, y2, valid);
    uint32_t kd;
    if (valid) {
      double xd = (double)logits[i];
      float s = (float)(1.0 / (1.0 + exp(-xd)));
      uint32_t u = __float_as_uint(s);
      kd = 0x7FFFFFFFu & ~u;        // descending-score -> ascending key
    } else {
      kd = 0xFF800000u;             // -inf key
    }
    keys[i] = kd;
    atomicAdd(&lh[kd >> 20], 1u);
  }
  __syncthreads();
  for (int b = tid; b < 4096; b += 1024)
    part1[blockIdx.x * 4096 + b] = lh[b];
  __threadfence();
  if (tid == 0) amLast = (atomicAdd(&ctrl[4], 1u) == NBLK1 - 1) ? 1u : 0u;
  __syncthreads();
  if (!amLast) return;
  // ---- findcut1 (this block only) ----
  __threadfence();
  __shared__ uint32_t part[1024];
  int t = tid;
  uint4 s4 = make_uint4(0u, 0u, 0u, 0u);     // thread t owns bins 4t..4t+3
  const uint4* p4 = (const uint4*)part1;
  for (int k = 0; k < NBLK1; k++) {
    uint4 q = p4[k * 1024 + t];
    s4.x += q.x; s4.y += q.y; s4.z += q.z; s4.w += q.w;
  }
  uint32_t tot = s4.x + s4.y + s4.z + s4.w;
  part[t] = tot;
  __syncthreads();
  uint32_t inc = tot;
  for (int off = 1; off < 1024; off <<= 1) {
    uint32_t u = (t >= off) ? part[t - off] : 0u;
    __syncthreads();
    inc += u;
    part[t] = inc;
    __syncthreads();
  }
  uint32_t ex = inc - tot;
  if (ex < PRE_K && inc >= PRE_K) {
    uint32_t run = ex;
    uint32_t binv[4] = { s4.x, s4.y, s4.z, s4.w };
    for (int b = 0; b < 4; b++) {
      if (run + binv[b] >= PRE_K) { ctrl[2] = 4 * t + b; ctrl[3] = run; break; }
      run += binv[b];
    }
  }
  if (t == 1023 && inc < PRE_K) { ctrl[2] = 4095u; ctrl[3] = inc; }
}

// ---- K2: refine next 8 bits in coarse bin; last block finds T20 ----
__global__ void __launch_bounds__(1024) k_hist2(const uint32_t* __restrict__ keys,
                                                uint32_t* __restrict__ ctrl,
                                                uint32_t* __restrict__ part2) {
  __shared__ uint32_t lh[256];
  __shared__ uint32_t amLast;
  int tid = threadIdx.x;
  if (tid < 256) lh[tid] = 0u;
  __syncthreads();
  uint32_t c = ctrl[2];
  for (int i = blockIdx.x * 1024 + tid; i < N_ANCH; i += NBLK1 * 1024) {
    uint32_t k = keys[i];
    if ((k >> 20) == c) atomicAdd(&lh[(k >> 12) & 0xFFu], 1u);
  }
  __syncthreads();
  if (tid < 256) part2[blockIdx.x * 256 + tid] = lh[tid];
  __threadfence();
  if (tid == 0) amLast = (atomicAdd(&ctrl[5], 1u) == NBLK1 - 1) ? 1u : 0u;
  __syncthreads();
  if (!amLast) return;
  __threadfence();
  // ---- findcut2: single wave, lane owns 4 sub-bins ----
  if (tid < 64) {
    int lane = tid;
    uint32_t b0 = 0, b1 = 0, b2 = 0, b3 = 0;
    for (int k = 0; k < NBLK1; k++) {
      const uint32_t* p = part2 + k * 256 + 4 * lane;
      b0 += p[0]; b1 += p[1]; b2 += p[2]; b3 += p[3];
    }
    uint32_t tot = b0 + b1 + b2 + b3;
    uint32_t inc = wave_iscan(tot, lane);
    uint32_t base = ctrl[3];
    uint32_t ex = inc - tot;
    if (base + ex < PRE_K && base + inc >= PRE_K) {
      uint32_t run = base + ex;
      uint32_t binv[4] = { b0, b1, b2, b3 };
      for (int b = 0; b < 4; b++) {
        if (run + binv[b] >= PRE_K) { ctrl[1] = (c << 8) | (uint32_t)(4 * lane + b); break; }
        run += binv[b];
      }
    }
    if (lane == 63 && base + inc < PRE_K) ctrl[1] = 0xFFFFFu;  // take everything
  }
}

// ---- K3: compact candidates (key prefix <= T), wave-aggregated atomic ----
__global__ void k_compact(const uint32_t* __restrict__ keys,
                          const uint32_t* __restrict__ ctrl,
                          uint32_t* __restrict__ cnt,
                          uint64_t* __restrict__ cand) {
  int i = blockIdx.x * blockDim.x + threadIdx.x;
  uint32_t T = ctrl[1];
  bool pass = (i < N_ANCH) && ((keys[i] >> 12) <= T);
  uint64_t m = __ballot(pass);
  if (pass) {
    int lane = threadIdx.x & 63;
    int leader = __ffsll((unsigned long long)m) - 1;
    uint32_t base = 0;
    if (lane == leader) base = atomicAdd(cnt, (uint32_t)__popcll((unsigned long long)m));
    base = (uint32_t)__shfl((int)base, leader);
    uint32_t pos = (uint32_t)__popcll((unsigned long long)(m & ((1ull << lane) - 1ull)));
    uint32_t p = base + pos;
    if (p < NS) cand[p] = ((uint64_t)keys[i] << 20) | (uint32_t)i;  // 52-bit packed
  }
}

// ---- K4: single-block LSD radix sort (4-bit x 13) + gather/decode epilogue ----
__global__ void __launch_bounds__(1024) k_sortgather(
    const uint32_t* __restrict__ ctrl,
    const uint64_t* __restrict__ cand,
    const float4* __restrict__ anchors,
    const float4* __restrict__ deltas,
    float4* __restrict__ boxes,
    uint32_t* __restrict__ valid) {
  __shared__ uint64_t buf[NS];            // 56 KiB
  __shared__ uint32_t hist[16 * TILES];   // 7 KiB   hist[d*TILES + t]
  __shared__ uint32_t dtot[16];
  __shared__ uint32_t dbase[16];
  __shared__ uint32_t skipf;
  int tid = threadIdx.x;
  int wave = tid >> 6, lane = tid & 63;
  uint32_t M = ctrl[0]; if (M > NS) M = NS;
  uint32_t T = ctrl[1];
  uint64_t pad = (T >= 0xFFFFFu) ? 0xFFFFFFFFFFFFFull
                                 : ((((uint64_t)T + 1) << 32) | 0xFFFFFFFFull);
  for (int i = tid; i < NS; i += 1024)
    buf[i] = (i < (int)M) ? cand[i] : pad;
  __syncthreads();
  uint64_t lmask_lt = (1ull << lane) - 1ull;

  for (int p = 0; p < PASSES; p++) {
    int shift = 4 * p;
    for (int i = tid; i < 16 * TILES; i += 1024) hist[i] = 0u;
    uint64_t v[TPW]; int dg[TPW]; int rk[TPW];
    #pragma unroll
    for (int k = 0; k < TPW; k++)
      v[k] = buf[(wave * TPW + k) * 64 + lane];
    __syncthreads();                       // B1: hist zeroed, all elements read
    #pragma unroll
    for (int k = 0; k < TPW; k++) {
      int d = (int)((v[k] >> shift) & 0xF);
      uint64_t m = ~0ull;
      #pragma unroll
      for (int b = 0; b < 4; b++) {
        uint64_t bal = __ballot((d >> b) & 1);
        m &= ((d >> b) & 1) ? bal : ~bal;
      }
      int r = (int)__popcll((unsigned long long)(m & lmask_lt));
      dg[k] = d; rk[k] = r;
      if (r == 0) hist[d * TILES + wave * TPW + k] = (uint32_t)__popcll((unsigned long long)m);
    }
    __syncthreads();                       // B2: hist counts complete
    {                                      // per-digit tile scan: wave w owns digit w
      int d = wave;
      uint32_t c0 = hist[d * TILES + lane];
      uint32_t c1 = (lane < TILES - 64) ? hist[d * TILES + 64 + lane] : 0u;
      uint32_t s0 = wave_iscan(c0, lane);
      uint32_t T0 = (uint32_t)__shfl((int)s0, 63, 64);
      uint32_t s1 = wave_iscan(c1, lane);
      uint32_t T1 = (uint32_t)__shfl((int)s1, 63, 64);
      hist[d * TILES + lane] = s0 - c0;
      if (lane < TILES - 64) hist[d * TILES + 64 + lane] = T0 + (s1 - c1);
      if (lane == 0) dtot[d] = T0 + T1;
    }
    __syncthreads();                       // B3
    if (wave == 0) {
      uint32_t x = (lane < 16) ? dtot[lane] : 0u;
      uint32_t xs = wave_iscan(x, lane);
      if (lane < 16) dbase[lane] = xs - x;
      if (lane == 0) skipf = 0u;
      if (lane < 16 && x == NS) skipf = 1u;   // single-digit pass -> identity scatter
    }
    __syncthreads();                       // B4
    if (!skipf) {
      #pragma unroll
      for (int k = 0; k < TPW; k++) {
        uint32_t dst = dbase[dg[k]] + hist[dg[k] * TILES + wave * TPW + k] + (uint32_t)rk[k];
        buf[dst] = v[k];
      }
    }
    __syncthreads();                       // B5
  }

  // ---- gather + decode epilogue ----
  for (int r = tid; r < ROWS; r += 1024) {
    if (r >= PRE_K) { boxes[r] = make_float4(0.f, 0.f, 0.f, 0.f); valid[r] = 0u; continue; }
    uint64_t kk = buf[r];
    uint32_t kd = (uint32_t)(kk >> 20);
    if (kk >= pad || kd >= 0xFF800000u) {
      boxes[r] = make_float4(0.f, 0.f, 0.f, 0.f); valid[r] = 0u; continue;
    }
    uint32_t idx = (uint32_t)(kk & 0xFFFFFu);
    float4 a = anchors[idx];
    float4 d = deltas[idx];
    float x1, y1, x2, y2; bool vv;
    decode_box(a.x, a.y, a.z, a.w, d.x, d.y, d.z, d.w, x1, y1, x2, y2, vv);
    boxes[r] = make_float4(x1, y1, x2, y2);
    valid[r] = 1u;
  }
}

// ---- K5: IoU bitmask matrix, row-major mask[row*WORDS + w] ----
__global__ void __launch_bounds__(64) k_iou(const float4* __restrict__ boxes,
                                            uint64_t* __restrict__ mask) {
  int by = blockIdx.y, bx = blockIdx.x;
  if (bx < by) return;               // only words w >= row's group are ever read
  __shared__ float4 cb[64];
  int t = threadIdx.x;
  cb[t] = boxes[bx * 64 + t];
  __syncthreads();
  int i = by * 64 + t;
  float4 b = boxes[i];
  float ax1 = b.x, ay1 = b.y, ax2 = b.z, ay2 = b.w;
  float areaA = __fmul_rn(__fsub_rn(ax2, ax1), __fsub_rn(ay2, ay1));
  uint64_t bits = 0;
  for (int c = 0; c < 64; c++) {
    float4 o = cb[c];
    float areaB = __fmul_rn(__fsub_rn(o.z, o.x), __fsub_rn(o.w, o.y));
    float ix1 = fmaxf(ax1, o.x), iy1 = fmaxf(ay1, o.y);
    float ix2 = fminf(ax2, o.z), iy2 = fminf(ay2, o.w);
    float iw = fmaxf(__fsub_rn(ix2, ix1), 0.0f);
    float ih = fmaxf(__fsub_rn(iy2, iy1), 0.0f);
    float inter = __fmul_rn(iw, ih);
    float uni = __fsub_rn(__fadd_rn(areaA, areaB), inter);
    bool sup = (uni > 0.0f) && (__fdiv_rn(inter, uni) > 0.7f);
    bits |= ((uint64_t)sup) << c;
  }
  mask[(size_t)i * WORDS + bx] = bits;
}

// wave-uniform 64-bit broadcast via v_readlane
__device__ __forceinline__ uint64_t bcast64(uint64_t v, int lane) {
  uint32_t lo = (uint32_t)__builtin_amdgcn_readlane((int)(uint32_t)v, lane);
  uint32_t hi = (uint32_t)__builtin_amdgcn_readlane((int)(uint32_t)(v >> 32), lane);
  return ((uint64_t)hi << 32) | lo;
}

// ---- K6: sequential NMS scan, single wave; fold only kept rows; prefetch next group ----
__global__ void __launch_bounds__(64) k_nms(const uint64_t* __restrict__ mask,
                                            const float4* __restrict__ boxes,
                                            const uint32_t* __restrict__ valid,
                                            float* __restrict__ out) {
  __shared__ uint32_t list[1024];
  int lane = threadIdx.x;
  int w0 = lane, w1 = lane + 64;
  uint64_t r0 = 0, r1 = 0;   // removed-bit words: lane owns words w0, w1
  int cnt = 0;
  uint64_t colv = mask[(size_t)lane * WORDS + 0];     // prefetch group 0
  uint32_t vf = valid[lane];
  for (int g = 0; g < WORDS; g++) {
    int base = g * 64;
    uint64_t colv_c = colv;
    uint32_t vf_c = vf;
    if (g + 1 < WORDS) {                              // prefetch group g+1
      colv = mask[(size_t)(base + 64 + lane) * WORDS + (g + 1)];
      vf = valid[base + 64 + lane];
    }
    uint64_t cur = (g < 64) ? bcast64(r0, g) : bcast64(r1, g - 64);
    uint64_t vmask = __ballot(vf_c != 0u);
    uint64_t alive = vmask & ~cur;
    uint64_t keptmask = 0;
    while (alive) {
      int r = __ffsll((unsigned long long)alive) - 1;
      keptmask |= 1ull << r;
      if (lane == 0) list[cnt] = (uint32_t)(base + r);
      cnt++;
      if (cnt >= POST_K) break;
      uint64_t m = bcast64(colv_c, r);   // row r's word g: in-group suppression
      alive &= ~m;
      alive &= ~(1ull << r);
    }
    if (cnt >= POST_K) break;
    uint64_t km = keptmask;              // fold only kept rows into later words
    while (km) {
      int r = __ffsll((unsigned long long)km) - 1;
      km &= km - 1;
      const uint64_t* row = mask + (size_t)(base + r) * WORDS;
      if (w0 > g) r0 |= row[w0];
      if (w1 > g && w1 < WORDS) r1 |= row[w1];
    }
  }
  __syncthreads();
  float4* outv = (float4*)out;
  for (int k = lane; k < POST_K; k += 64)
    outv[k] = (k < cnt) ? boxes[list[k]] : make_float4(0.f, 0.f, 0.f, 0.f);
}

extern "C" void kernel_launch(void* const* d_in, const int* in_sizes, int n_in,
                              void* d_out, int out_size, void* d_ws, size_t ws_size,
                              hipStream_t stream) {
  const float4* anchors = (const float4*)d_in[1];
  const float4* deltas  = (const float4*)d_in[2];
  const float*  logits  = (const float*)d_in[3];
  char* w = (char*)d_ws;
  uint32_t* keys  = (uint32_t*)(w + OFF_KEYS);
  uint32_t* part1 = (uint32_t*)(w + OFF_PART1);
  uint32_t* part2 = (uint32_t*)(w + OFF_PART2);
  uint32_t* ctrl  = (uint32_t*)(w + OFF_CTRL);
  uint64_t* cand  = (uint64_t*)(w + OFF_CAND);
  float4*   boxes = (float4*)(w + OFF_BOXES);
  uint32_t* valid = (uint32_t*)(w + OFF_VALID);
  uint64_t* mask  = (uint64_t*)(w + OFF_MASK);
  float*    out   = (float*)d_out;

  hipMemsetAsync(w + OFF_CTRL, 0, 256, stream);   // counters only

  k_score<<<NBLK1, 1024, 0, stream>>>(anchors, deltas, logits, keys, part1, ctrl);
  k_hist2<<<NBLK1, 1024, 0, stream>>>(keys, ctrl, part2);
  k_compact<<<(N_ANCH + 255) / 256, 256, 0, stream>>>(keys, ctrl, &ctrl[0], cand);
  k_sortgather<<<1, 1024, 0, stream>>>(ctrl, cand, anchors, deltas, boxes, valid);
  k_iou<<<dim3(WORDS, WORDS), 64, 0, stream>>>(boxes, mask);
  k_nms<<<1, 64, 0, stream>>>(mask, boxes, valid, out);
}

// Round 5
// 447.455 us; speedup vs baseline: 1.9851x; 1.9851x over previous
//
#include <hip/hip_runtime.h>
#include <stdint.h>
#include <math.h>

#define N_ANCH   1000000
#define PRE_K    6000
#define POST_K   1000
#define WORDS    94            // ceil(6000/64) -> 6016 bit columns
#define ROWS     6016          // WORDS*64
#define W_IMG    1333.0f
#define H_IMG    800.0f
#define NBLK1    64            // histogram blocks (x1024 threads)

// radix sort config (single block)
#define NS       7168          // sort capacity (112 tiles of 64)
#define TILES    112
#define TPW      7             // tiles per wave (16 waves)
#define PASSES   13            // 13 x 4 bits = 52 = 32-bit key + 20-bit idx

// ws layout (bytes)
#define OFF_KEYS   0x000000u   // u32[1e6]
#define OFF_PART1  0x400000u   // u32[NBLK1*4096] = 1 MiB
#define OFF_PART2  0x500000u   // u32[NBLK1*256]  = 64 KiB
#define OFF_CTRL   0x510000u   // [0]=count [1]=T20 [2]=coarse c [3]=base [4],[5]=done ctrs
#define OFF_CAND   0x510100u   // u64[NS] 56 KiB
#define OFF_BOXES  0x51F000u   // float4[6016]
#define OFF_VALID  0x537000u   // u32[6016]
#define OFF_MASK   0x540000u   // u64[6016*94] row-major: mask[row*WORDS + w]

__device__ __forceinline__ float ref_exp(float v) {
  return (float)exp((double)v);   // correctly-rounded f32 exp via double
}

__device__ __forceinline__ void decode_box(float ax, float ay, float az, float aw,
                                           float dx, float dy, float dz, float dw,
                                           float& x1, float& y1, float& x2, float& y2,
                                           bool& valid) {
  // bit-exact replica of reference fp32 op order (no FMA contraction)
  float wa = __fsub_rn(az, ax);
  float ha = __fsub_rn(aw, ay);
  float xa = __fadd_rn(ax, __fmul_rn(0.5f, wa));
  float ya = __fadd_rn(ay, __fmul_rn(0.5f, ha));
  float x  = __fadd_rn(__fmul_rn(dx, wa), xa);
  float y  = __fadd_rn(__fmul_rn(dy, ha), ya);
  float w  = __fmul_rn(ref_exp(dz), wa);
  float h  = __fmul_rn(ref_exp(dw), ha);
  float hw = __fmul_rn(0.5f, w);
  float hh = __fmul_rn(0.5f, h);
  x1 = fminf(fmaxf(__fsub_rn(x, hw), 0.0f), W_IMG - 1.0f);
  y1 = fminf(fmaxf(__fsub_rn(y, hh), 0.0f), H_IMG - 1.0f);
  x2 = fminf(fmaxf(__fadd_rn(x, hw), 0.0f), W_IMG - 1.0f);
  y2 = fminf(fmaxf(__fadd_rn(y, hh), 0.0f), H_IMG - 1.0f);
  valid = (__fsub_rn(x2, x1) >= 16.0f) && (__fsub_rn(y2, y1) >= 16.0f);
}

__device__ __forceinline__ uint32_t wave_iscan(uint32_t x, int lane) {
  #pragma unroll
  for (int off = 1; off < 64; off <<= 1) {
    uint32_t u = __shfl_up(x, off, 64);
    if (lane >= off) x += u;
  }
  return x;
}

// ---- K1: decode + score key + 12-bit LDS histogram; last block finds coarse cut ----
__global__ void __launch_bounds__(1024) k_score(const float4* __restrict__ anchors,
                                                const float4* __restrict__ deltas,
                                                const float*  __restrict__ logits,
                                                uint32_t* __restrict__ keys,
                                                uint32_t* __restrict__ part1,
                                                uint32_t* __restrict__ ctrl) {
  __shared__ uint32_t lh[4096];
  __shared__ uint32_t amLast;
  int tid = threadIdx.x;
  for (int b = tid; b < 4096; b += 1024) lh[b] = 0u;
  __syncthreads();
  for (int i = blockIdx.x * 1024 + tid; i < N_ANCH; i += NBLK1 * 1024) {
    float4 a = anchors[i];
    float4 d = deltas[i];
    float x1, y1, x2, y2; bool valid;
    decode_box(a.x, a.y, a.z, a.w, d.x, d.y, d.z, d.w, x1, y1, x2, y2, valid);
    uint32_t kd;
    if (valid) {
      double xd = (double)logits[i];
      float s = (float)(1.0 / (1.0 + exp(-xd)));
      uint32_t u = __float_as_uint(s);
      kd = 0x7FFFFFFFu & ~u;        // descending-score -> ascending key
    } else {
      kd = 0xFF800000u;             // -inf key
    }
    keys[i] = kd;
    atomicAdd(&lh[kd >> 20], 1u);
  }
  __syncthreads();
  for (int b = tid; b < 4096; b += 1024)
    part1[blockIdx.x * 4096 + b] = lh[b];
  __threadfence();
  if (tid == 0) amLast = (atomicAdd(&ctrl[4], 1u) == NBLK1 - 1) ? 1u : 0u;
  __syncthreads();
  if (!amLast) return;
  // ---- findcut1 (this block only) ----
  __threadfence();
  __shared__ uint32_t part[1024];
  int t = tid;
  uint4 s4 = make_uint4(0u, 0u, 0u, 0u);     // thread t owns bins 4t..4t+3
  const uint4* p4 = (const uint4*)part1;
  for (int k = 0; k < NBLK1; k++) {
    uint4 q = p4[k * 1024 + t];
    s4.x += q.x; s4.y += q.y; s4.z += q.z; s4.w += q.w;
  }
  uint32_t tot = s4.x + s4.y + s4.z + s4.w;
  part[t] = tot;
  __syncthreads();
  uint32_t inc = tot;
  for (int off = 1; off < 1024; off <<= 1) {
    uint32_t u = (t >= off) ? part[t - off] : 0u;
    __syncthreads();
    inc += u;
    part[t] = inc;
    __syncthreads();
  }
  uint32_t ex = inc - tot;
  if (ex < PRE_K && inc >= PRE_K) {
    uint32_t run = ex;
    uint32_t binv[4] = { s4.x, s4.y, s4.z, s4.w };
    for (int b = 0; b < 4; b++) {
      if (run + binv[b] >= PRE_K) { ctrl[2] = 4 * t + b; ctrl[3] = run; break; }
      run += binv[b];
    }
  }
  if (t == 1023 && inc < PRE_K) { ctrl[2] = 4095u; ctrl[3] = inc; }
}

// ---- K2: refine next 8 bits in coarse bin; last block finds T20 ----
__global__ void __launch_bounds__(1024) k_hist2(const uint32_t* __restrict__ keys,
                                                uint32_t* __restrict__ ctrl,
                                                uint32_t* __restrict__ part2) {
  __shared__ uint32_t lh[256];
  __shared__ uint32_t amLast;
  int tid = threadIdx.x;
  if (tid < 256) lh[tid] = 0u;
  __syncthreads();
  uint32_t c = ctrl[2];
  for (int i = blockIdx.x * 1024 + tid; i < N_ANCH; i += NBLK1 * 1024) {
    uint32_t k = keys[i];
    if ((k >> 20) == c) atomicAdd(&lh[(k >> 12) & 0xFFu], 1u);
  }
  __syncthreads();
  if (tid < 256) part2[blockIdx.x * 256 + tid] = lh[tid];
  __threadfence();
  if (tid == 0) amLast = (atomicAdd(&ctrl[5], 1u) == NBLK1 - 1) ? 1u : 0u;
  __syncthreads();
  if (!amLast) return;
  __threadfence();
  // ---- findcut2: single wave, lane owns 4 sub-bins ----
  if (tid < 64) {
    int lane = tid;
    uint32_t b0 = 0, b1 = 0, b2 = 0, b3 = 0;
    for (int k = 0; k < NBLK1; k++) {
      const uint32_t* p = part2 + k * 256 + 4 * lane;
      b0 += p[0]; b1 += p[1]; b2 += p[2]; b3 += p[3];
    }
    uint32_t tot = b0 + b1 + b2 + b3;
    uint32_t inc = wave_iscan(tot, lane);
    uint32_t base = ctrl[3];
    uint32_t ex = inc - tot;
    if (base + ex < PRE_K && base + inc >= PRE_K) {
      uint32_t run = base + ex;
      uint32_t binv[4] = { b0, b1, b2, b3 };
      for (int b = 0; b < 4; b++) {
        if (run + binv[b] >= PRE_K) { ctrl[1] = (c << 8) | (uint32_t)(4 * lane + b); break; }
        run += binv[b];
      }
    }
    if (lane == 63 && base + inc < PRE_K) ctrl[1] = 0xFFFFFu;  // take everything
  }
}

// ---- K3: compact candidates (key prefix <= T), wave-aggregated atomic ----
__global__ void k_compact(const uint32_t* __restrict__ keys,
                          const uint32_t* __restrict__ ctrl,
                          uint32_t* __restrict__ cnt,
                          uint64_t* __restrict__ cand) {
  int i = blockIdx.x * blockDim.x + threadIdx.x;
  uint32_t T = ctrl[1];
  bool pass = (i < N_ANCH) && ((keys[i] >> 12) <= T);
  uint64_t m = __ballot(pass);
  if (pass) {
    int lane = threadIdx.x & 63;
    int leader = __ffsll((unsigned long long)m) - 1;
    uint32_t base = 0;
    if (lane == leader) base = atomicAdd(cnt, (uint32_t)__popcll((unsigned long long)m));
    base = (uint32_t)__shfl((int)base, leader);
    uint32_t pos = (uint32_t)__popcll((unsigned long long)(m & ((1ull << lane) - 1ull)));
    uint32_t p = base + pos;
    if (p < NS) cand[p] = ((uint64_t)keys[i] << 20) | (uint32_t)i;  // 52-bit packed
  }
}

// ---- K4: single-block LSD radix sort (4-bit x 13) + gather/decode epilogue ----
__global__ void __launch_bounds__(1024) k_sortgather(
    const uint32_t* __restrict__ ctrl,
    const uint64_t* __restrict__ cand,
    const float4* __restrict__ anchors,
    const float4* __restrict__ deltas,
    float4* __restrict__ boxes,
    uint32_t* __restrict__ valid) {
  __shared__ uint64_t buf[NS];            // 56 KiB
  __shared__ uint32_t hist[16 * TILES];   // 7 KiB   hist[d*TILES + t]
  __shared__ uint32_t dtot[16];
  __shared__ uint32_t dbase[16];
  __shared__ uint32_t skipf;
  int tid = threadIdx.x;
  int wave = tid >> 6, lane = tid & 63;
  uint32_t M = ctrl[0]; if (M > NS) M = NS;
  uint32_t T = ctrl[1];
  uint64_t pad = (T >= 0xFFFFFu) ? 0xFFFFFFFFFFFFFull
                                 : ((((uint64_t)T + 1) << 32) | 0xFFFFFFFFull);
  for (int i = tid; i < NS; i += 1024)
    buf[i] = (i < (int)M) ? cand[i] : pad;
  __syncthreads();
  uint64_t lmask_lt = (1ull << lane) - 1ull;

  for (int p = 0; p < PASSES; p++) {
    int shift = 4 * p;
    for (int i = tid; i < 16 * TILES; i += 1024) hist[i] = 0u;
    uint64_t v[TPW]; int dg[TPW]; int rk[TPW];
    #pragma unroll
    for (int k = 0; k < TPW; k++)
      v[k] = buf[(wave * TPW + k) * 64 + lane];
    __syncthreads();                       // B1: hist zeroed, all elements read
    #pragma unroll
    for (int k = 0; k < TPW; k++) {
      int d = (int)((v[k] >> shift) & 0xF);
      uint64_t m = ~0ull;
      #pragma unroll
      for (int b = 0; b < 4; b++) {
        uint64_t bal = __ballot((d >> b) & 1);
        m &= ((d >> b) & 1) ? bal : ~bal;
      }
      int r = (int)__popcll((unsigned long long)(m & lmask_lt));
      dg[k] = d; rk[k] = r;
      if (r == 0) hist[d * TILES + wave * TPW + k] = (uint32_t)__popcll((unsigned long long)m);
    }
    __syncthreads();                       // B2: hist counts complete
    {                                      // per-digit tile scan: wave w owns digit w
      int d = wave;
      uint32_t c0 = hist[d * TILES + lane];
      uint32_t c1 = (lane < TILES - 64) ? hist[d * TILES + 64 + lane] : 0u;
      uint32_t s0 = wave_iscan(c0, lane);
      uint32_t T0 = (uint32_t)__shfl((int)s0, 63, 64);
      uint32_t s1 = wave_iscan(c1, lane);
      uint32_t T1 = (uint32_t)__shfl((int)s1, 63, 64);
      hist[d * TILES + lane] = s0 - c0;
      if (lane < TILES - 64) hist[d * TILES + 64 + lane] = T0 + (s1 - c1);
      if (lane == 0) dtot[d] = T0 + T1;
    }
    __syncthreads();                       // B3
    if (wave == 0) {
      uint32_t x = (lane < 16) ? dtot[lane] : 0u;
      uint32_t xs = wave_iscan(x, lane);
      if (lane < 16) dbase[lane] = xs - x;
      if (lane == 0) skipf = 0u;
      if (lane < 16 && x == NS) skipf = 1u;   // single-digit pass -> identity scatter
    }
    __syncthreads();                       // B4
    if (!skipf) {
      #pragma unroll
      for (int k = 0; k < TPW; k++) {
        uint32_t dst = dbase[dg[k]] + hist[dg[k] * TILES + wave * TPW + k] + (uint32_t)rk[k];
        buf[dst] = v[k];
      }
    }
    __syncthreads();                       // B5
  }

  // ---- gather + decode epilogue ----
  for (int r = tid; r < ROWS; r += 1024) {
    if (r >= PRE_K) { boxes[r] = make_float4(0.f, 0.f, 0.f, 0.f); valid[r] = 0u; continue; }
    uint64_t kk = buf[r];
    uint32_t kd = (uint32_t)(kk >> 20);
    if (kk >= pad || kd >= 0xFF800000u) {
      boxes[r] = make_float4(0.f, 0.f, 0.f, 0.f); valid[r] = 0u; continue;
    }
    uint32_t idx = (uint32_t)(kk & 0xFFFFFu);
    float4 a = anchors[idx];
    float4 d = deltas[idx];
    float x1, y1, x2, y2; bool vv;
    decode_box(a.x, a.y, a.z, a.w, d.x, d.y, d.z, d.w, x1, y1, x2, y2, vv);
    boxes[r] = make_float4(x1, y1, x2, y2);
    valid[r] = 1u;
  }
}

// ---- K5: IoU bitmask matrix, row-major mask[row*WORDS + w] ----
__global__ void __launch_bounds__(64) k_iou(const float4* __restrict__ boxes,
                                            uint64_t* __restrict__ mask) {
  int by = blockIdx.y, bx = blockIdx.x;
  if (bx < by) return;               // only words w >= row's group are ever read
  __shared__ float4 cb[64];
  int t = threadIdx.x;
  cb[t] = boxes[bx * 64 + t];
  __syncthreads();
  int i = by * 64 + t;
  float4 b = boxes[i];
  float ax1 = b.x, ay1 = b.y, ax2 = b.z, ay2 = b.w;
  float areaA = __fmul_rn(__fsub_rn(ax2, ax1), __fsub_rn(ay2, ay1));
  uint64_t bits = 0;
  for (int c = 0; c < 64; c++) {
    float4 o = cb[c];
    float areaB = __fmul_rn(__fsub_rn(o.z, o.x), __fsub_rn(o.w, o.y));
    float ix1 = fmaxf(ax1, o.x), iy1 = fmaxf(ay1, o.y);
    float ix2 = fminf(ax2, o.z), iy2 = fminf(ay2, o.w);
    float iw = fmaxf(__fsub_rn(ix2, ix1), 0.0f);
    float ih = fmaxf(__fsub_rn(iy2, iy1), 0.0f);
    float inter = __fmul_rn(iw, ih);
    float uni = __fsub_rn(__fadd_rn(areaA, areaB), inter);
    bool sup = (uni > 0.0f) && (__fdiv_rn(inter, uni) > 0.7f);
    bits |= ((uint64_t)sup) << c;
  }
  mask[(size_t)i * WORDS + bx] = bits;
}

// wave-uniform 64-bit broadcast via v_readlane
__device__ __forceinline__ uint64_t bcast64(uint64_t v, int lane) {
  uint32_t lo = (uint32_t)__builtin_amdgcn_readlane((int)(uint32_t)v, lane);
  uint32_t hi = (uint32_t)__builtin_amdgcn_readlane((int)(uint32_t)(v >> 32), lane);
  return ((uint64_t)hi << 32) | lo;
}

#define FOLD_CHUNK 24

// ---- K6: sequential NMS scan, single wave; BATCHED selective fold ----
__global__ void __launch_bounds__(64) k_nms(const uint64_t* __restrict__ mask,
                                            const float4* __restrict__ boxes,
                                            const uint32_t* __restrict__ valid,
                                            float* __restrict__ out) {
  __shared__ uint32_t list[1024];
  int lane = threadIdx.x;
  int w0 = lane, w1 = lane + 64;
  int w1c = (w1 < WORDS) ? w1 : 0;   // clamped safe load address
  uint64_t r0 = 0, r1 = 0;           // removed-bit words: lane owns words w0, w1
  int cnt = 0;
  uint64_t colv = mask[(size_t)lane * WORDS + 0];     // prefetch group 0
  uint32_t vf = valid[lane];
  for (int g = 0; g < WORDS; g++) {
    int base = g * 64;
    uint64_t colv_c = colv;
    uint32_t vf_c = vf;
    if (g + 1 < WORDS) {                              // prefetch group g+1
      colv = mask[(size_t)(base + 64 + lane) * WORDS + (g + 1)];
      vf = valid[base + 64 + lane];
    }
    uint64_t cur = (g < 64) ? bcast64(r0, g) : bcast64(r1, g - 64);
    uint64_t vmask = __ballot(vf_c != 0u);
    uint64_t alive = vmask & ~cur;
    uint64_t keptmask = 0;
    while (alive) {                                   // serial decision chain
      int r = __ffsll((unsigned long long)alive) - 1;
      keptmask |= 1ull << r;
      if (lane == 0) list[cnt] = (uint32_t)(base + r);
      cnt++;
      if (cnt >= POST_K) break;
      uint64_t m = bcast64(colv_c, r);                // row r's in-group word
      alive &= ~m;
      alive &= ~(1ull << r);
    }
    if (cnt >= POST_K) break;
    // ---- batched fold: chunks of FOLD_CHUNK kept rows, one vmcnt drain each ----
    uint64_t kmo = keptmask;
    uint64_t acc0 = 0, acc1 = 0;
    while (kmo) {
      uint64_t va[FOLD_CHUNK], vb[FOLD_CHUNK];
      uint32_t hasm = 0;
      uint64_t kml = kmo;
      #pragma unroll
      for (int i = 0; i < FOLD_CHUNK; i++) {          // issue all loads (independent)
        int r = (kml != 0) ? (__ffsll((unsigned long long)kml) - 1) : 0;
        hasm |= (kml != 0) ? (1u << i) : 0u;
        const uint64_t* row = mask + (size_t)(base + r) * WORDS;
        va[i] = row[w0];
        vb[i] = row[w1c];
        kml &= kml - 1;
      }
      kmo = kml;
      #pragma unroll
      for (int i = 0; i < FOLD_CHUNK; i++) {          // drain + select-OR
        uint64_t s = 0ull - (uint64_t)((hasm >> i) & 1u);
        acc0 |= va[i] & s;
        acc1 |= vb[i] & s;
      }
    }
    if (w0 > g) r0 |= acc0;
    if (w1 > g && w1 < WORDS) r1 |= acc1;
  }
  __syncthreads();
  float4* outv = (float4*)out;
  for (int k = lane; k < POST_K; k += 64)
    outv[k] = (k < cnt) ? boxes[list[k]] : make_float4(0.f, 0.f, 0.f, 0.f);
}

extern "C" void kernel_launch(void* const* d_in, const int* in_sizes, int n_in,
                              void* d_out, int out_size, void* d_ws, size_t ws_size,
                              hipStream_t stream) {
  const float4* anchors = (const float4*)d_in[1];
  const float4* deltas  = (const float4*)d_in[2];
  const float*  logits  = (const float*)d_in[3];
  char* w = (char*)d_ws;
  uint32_t* keys  = (uint32_t*)(w + OFF_KEYS);
  uint32_t* part1 = (uint32_t*)(w + OFF_PART1);
  uint32_t* part2 = (uint32_t*)(w + OFF_PART2);
  uint32_t* ctrl  = (uint32_t*)(w + OFF_CTRL);
  uint64_t* cand  = (uint64_t*)(w + OFF_CAND);
  float4*   boxes = (float4*)(w + OFF_BOXES);
  uint32_t* valid = (uint32_t*)(w + OFF_VALID);
  uint64_t* mask  = (uint64_t*)(w + OFF_MASK);
  float*    out   = (float*)d_out;

  hipMemsetAsync(w + OFF_CTRL, 0, 256, stream);   // counters only

  k_score<<<NBLK1, 1024, 0, stream>>>(anchors, deltas, logits, keys, part1, ctrl);
  k_hist2<<<NBLK1, 1024, 0, stream>>>(keys, ctrl, part2);
  k_compact<<<(N_ANCH + 255) / 256, 256, 0, stream>>>(keys, ctrl, &ctrl[0], cand);
  k_sortgather<<<1, 1024, 0, stream>>>(ctrl, cand, anchors, deltas, boxes, valid);
  k_iou<<<dim3(WORDS, WORDS), 64, 0, stream>>>(boxes, mask);
  k_nms<<<1, 64, 0, stream>>>(mask, boxes, valid, out);
}

// Round 6
// 445.396 us; speedup vs baseline: 1.9942x; 1.0046x over previous
//
#include <hip/hip_runtime.h>
#include <stdint.h>
#include <math.h>

#define N_ANCH   1000000
#define PRE_K    6000
#define POST_K   1000
#define WORDS    94            // ceil(6000/64) -> 6016 bit columns
#define ROWS     6016          // WORDS*64
#define W_IMG    1333.0f
#define H_IMG    800.0f
#define NBLK1    64            // histogram blocks (x1024 threads)

// radix sort config (single block)
#define NS       7168          // sort capacity (112 tiles of 64)
#define TILES    112
#define TPW      7             // tiles per wave (16 waves)
#define PASSES   13            // 13 x 4 bits = 52 = 32-bit key + 20-bit idx

// ws layout (bytes)
#define OFF_KEYS   0x000000u   // u32[1e6]
#define OFF_PART1  0x400000u   // u32[NBLK1*4096] = 1 MiB
#define OFF_PART2  0x500000u   // u32[NBLK1*256]  = 64 KiB
#define OFF_CTRL   0x510000u   // [0]=count [1]=T20 [2]=coarse c [3]=base [4],[5]=done ctrs
#define OFF_CAND   0x510100u   // u64[NS] 56 KiB
#define OFF_BOXES  0x51F000u   // float4[6016]
#define OFF_VALID  0x537000u   // u32[6016]
#define OFF_MASK   0x540000u   // u64[6016*94] row-major: mask[row*WORDS + w]

__device__ __forceinline__ float ref_exp(float v) {
  return (float)exp((double)v);   // correctly-rounded f32 exp via double
}

__device__ __forceinline__ void decode_box(float ax, float ay, float az, float aw,
                                           float dx, float dy, float dz, float dw,
                                           float& x1, float& y1, float& x2, float& y2,
                                           bool& valid) {
  // bit-exact replica of reference fp32 op order (no FMA contraction)
  float wa = __fsub_rn(az, ax);
  float ha = __fsub_rn(aw, ay);
  float xa = __fadd_rn(ax, __fmul_rn(0.5f, wa));
  float ya = __fadd_rn(ay, __fmul_rn(0.5f, ha));
  float x  = __fadd_rn(__fmul_rn(dx, wa), xa);
  float y  = __fadd_rn(__fmul_rn(dy, ha), ya);
  float w  = __fmul_rn(ref_exp(dz), wa);
  float h  = __fmul_rn(ref_exp(dw), ha);
  float hw = __fmul_rn(0.5f, w);
  float hh = __fmul_rn(0.5f, h);
  x1 = fminf(fmaxf(__fsub_rn(x, hw), 0.0f), W_IMG - 1.0f);
  y1 = fminf(fmaxf(__fsub_rn(y, hh), 0.0f), H_IMG - 1.0f);
  x2 = fminf(fmaxf(__fadd_rn(x, hw), 0.0f), W_IMG - 1.0f);
  y2 = fminf(fmaxf(__fadd_rn(y, hh), 0.0f), H_IMG - 1.0f);
  valid = (__fsub_rn(x2, x1) >= 16.0f) && (__fsub_rn(y2, y1) >= 16.0f);
}

__device__ __forceinline__ uint32_t wave_iscan(uint32_t x, int lane) {
  #pragma unroll
  for (int off = 1; off < 64; off <<= 1) {
    uint32_t u = __shfl_up(x, off, 64);
    if (lane >= off) x += u;
  }
  return x;
}

// ---- K1: decode + score key + 12-bit LDS histogram; last block finds coarse cut ----
__global__ void __launch_bounds__(1024) k_score(const float4* __restrict__ anchors,
                                                const float4* __restrict__ deltas,
                                                const float*  __restrict__ logits,
                                                uint32_t* __restrict__ keys,
                                                uint32_t* __restrict__ part1,
                                                uint32_t* __restrict__ ctrl) {
  __shared__ uint32_t lh[4096];
  __shared__ uint32_t amLast;
  int tid = threadIdx.x;
  int lane = tid & 63;
  for (int b = tid; b < 4096; b += 1024) lh[b] = 0u;
  __syncthreads();
  for (int i = blockIdx.x * 1024 + tid; i < N_ANCH; i += NBLK1 * 1024) {
    float4 a = anchors[i];
    float4 d = deltas[i];
    float x1, y1, x2, y2; bool valid;
    decode_box(a.x, a.y, a.z, a.w, d.x, d.y, d.z, d.w, x1, y1, x2, y2, valid);
    uint32_t kd;
    if (valid) {
      double xd = (double)logits[i];
      float s = (float)(1.0 / (1.0 + exp(-xd)));
      uint32_t u = __float_as_uint(s);
      kd = 0x7FFFFFFFu & ~u;        // descending-score -> ascending key
    } else {
      kd = 0xFF800000u;             // -inf key (bin 0xFF8)
    }
    keys[i] = kd;
    // ballot-aggregate the hot invalid bin: one LDS atomic per wave
    uint64_t invb = __ballot(!valid);
    if (valid) {
      atomicAdd(&lh[kd >> 20], 1u);
    } else if ((invb & ((1ull << lane) - 1ull)) == 0ull) {
      atomicAdd(&lh[0xFF8u], (uint32_t)__popcll((unsigned long long)invb));
    }
  }
  __syncthreads();
  for (int b = tid; b < 4096; b += 1024)
    part1[blockIdx.x * 4096 + b] = lh[b];
  __threadfence();
  if (tid == 0) amLast = (atomicAdd(&ctrl[4], 1u) == NBLK1 - 1) ? 1u : 0u;
  __syncthreads();
  if (!amLast) return;
  // ---- findcut1 (this block only) ----
  __threadfence();
  __shared__ uint32_t part[1024];
  int t = tid;
  uint4 s4 = make_uint4(0u, 0u, 0u, 0u);     // thread t owns bins 4t..4t+3
  const uint4* p4 = (const uint4*)part1;
  for (int k = 0; k < NBLK1; k++) {
    uint4 q = p4[k * 1024 + t];
    s4.x += q.x; s4.y += q.y; s4.z += q.z; s4.w += q.w;
  }
  uint32_t tot = s4.x + s4.y + s4.z + s4.w;
  part[t] = tot;
  __syncthreads();
  uint32_t inc = tot;
  for (int off = 1; off < 1024; off <<= 1) {
    uint32_t u = (t >= off) ? part[t - off] : 0u;
    __syncthreads();
    inc += u;
    part[t] = inc;
    __syncthreads();
  }
  uint32_t ex = inc - tot;
  if (ex < PRE_K && inc >= PRE_K) {
    uint32_t run = ex;
    uint32_t binv[4] = { s4.x, s4.y, s4.z, s4.w };
    for (int b = 0; b < 4; b++) {
      if (run + binv[b] >= PRE_K) { ctrl[2] = 4 * t + b; ctrl[3] = run; break; }
      run += binv[b];
    }
  }
  if (t == 1023 && inc < PRE_K) { ctrl[2] = 4095u; ctrl[3] = inc; }
}

// ---- K2: refine next 8 bits in coarse bin; last block finds T20 ----
__global__ void __launch_bounds__(1024) k_hist2(const uint32_t* __restrict__ keys,
                                                uint32_t* __restrict__ ctrl,
                                                uint32_t* __restrict__ part2) {
  __shared__ uint32_t lh[256];
  __shared__ uint32_t amLast;
  int tid = threadIdx.x;
  if (tid < 256) lh[tid] = 0u;
  __syncthreads();
  uint32_t c = ctrl[2];
  for (int i = blockIdx.x * 1024 + tid; i < N_ANCH; i += NBLK1 * 1024) {
    uint32_t k = keys[i];
    if ((k >> 20) == c) atomicAdd(&lh[(k >> 12) & 0xFFu], 1u);
  }
  __syncthreads();
  if (tid < 256) part2[blockIdx.x * 256 + tid] = lh[tid];
  __threadfence();
  if (tid == 0) amLast = (atomicAdd(&ctrl[5], 1u) == NBLK1 - 1) ? 1u : 0u;
  __syncthreads();
  if (!amLast) return;
  __threadfence();
  // ---- findcut2: single wave, lane owns 4 sub-bins ----
  if (tid < 64) {
    int lane = tid;
    uint32_t b0 = 0, b1 = 0, b2 = 0, b3 = 0;
    for (int k = 0; k < NBLK1; k++) {
      const uint32_t* p = part2 + k * 256 + 4 * lane;
      b0 += p[0]; b1 += p[1]; b2 += p[2]; b3 += p[3];
    }
    uint32_t tot = b0 + b1 + b2 + b3;
    uint32_t inc = wave_iscan(tot, lane);
    uint32_t base = ctrl[3];
    uint32_t ex = inc - tot;
    if (base + ex < PRE_K && base + inc >= PRE_K) {
      uint32_t run = base + ex;
      uint32_t binv[4] = { b0, b1, b2, b3 };
      for (int b = 0; b < 4; b++) {
        if (run + binv[b] >= PRE_K) { ctrl[1] = (c << 8) | (uint32_t)(4 * lane + b); break; }
        run += binv[b];
      }
    }
    if (lane == 63 && base + inc < PRE_K) ctrl[1] = 0xFFFFFu;  // take everything
  }
}

// ---- K3: compact candidates (key prefix <= T), wave-aggregated atomic ----
__global__ void k_compact(const uint32_t* __restrict__ keys,
                          const uint32_t* __restrict__ ctrl,
                          uint32_t* __restrict__ cnt,
                          uint64_t* __restrict__ cand) {
  int i = blockIdx.x * blockDim.x + threadIdx.x;
  uint32_t T = ctrl[1];
  bool pass = (i < N_ANCH) && ((keys[i] >> 12) <= T);
  uint64_t m = __ballot(pass);
  if (pass) {
    int lane = threadIdx.x & 63;
    int leader = __ffsll((unsigned long long)m) - 1;
    uint32_t base = 0;
    if (lane == leader) base = atomicAdd(cnt, (uint32_t)__popcll((unsigned long long)m));
    base = (uint32_t)__shfl((int)base, leader);
    uint32_t pos = (uint32_t)__popcll((unsigned long long)(m & ((1ull << lane) - 1ull)));
    uint32_t p = base + pos;
    if (p < NS) cand[p] = ((uint64_t)keys[i] << 20) | (uint32_t)i;  // 52-bit packed
  }
}

// ---- K4: single-block LSD radix sort (4-bit x 13) + gather/decode epilogue ----
__global__ void __launch_bounds__(1024) k_sortgather(
    const uint32_t* __restrict__ ctrl,
    const uint64_t* __restrict__ cand,
    const float4* __restrict__ anchors,
    const float4* __restrict__ deltas,
    float4* __restrict__ boxes,
    uint32_t* __restrict__ valid) {
  __shared__ uint64_t buf[NS];            // 56 KiB
  __shared__ uint32_t hist[16 * TILES];   // 7 KiB   hist[d*TILES + t]
  __shared__ uint32_t dtot[16];
  __shared__ uint32_t dbase[16];
  __shared__ uint32_t skipf;
  int tid = threadIdx.x;
  int wave = tid >> 6, lane = tid & 63;
  uint32_t M = ctrl[0]; if (M > NS) M = NS;
  uint32_t T = ctrl[1];
  uint64_t pad = (T >= 0xFFFFFu) ? 0xFFFFFFFFFFFFFull
                                 : ((((uint64_t)T + 1) << 32) | 0xFFFFFFFFull);
  for (int i = tid; i < NS; i += 1024)
    buf[i] = (i < (int)M) ? cand[i] : pad;
  __syncthreads();
  uint64_t lmask_lt = (1ull << lane) - 1ull;

  for (int p = 0; p < PASSES; p++) {
    int shift = 4 * p;
    for (int i = tid; i < 16 * TILES; i += 1024) hist[i] = 0u;
    uint64_t v[TPW]; int dg[TPW]; int rk[TPW];
    #pragma unroll
    for (int k = 0; k < TPW; k++)
      v[k] = buf[(wave * TPW + k) * 64 + lane];
    __syncthreads();                       // B1: hist zeroed, all elements read
    #pragma unroll
    for (int k = 0; k < TPW; k++) {
      int d = (int)((v[k] >> shift) & 0xF);
      uint64_t m = ~0ull;
      #pragma unroll
      for (int b = 0; b < 4; b++) {
        uint64_t bal = __ballot((d >> b) & 1);
        m &= ((d >> b) & 1) ? bal : ~bal;
      }
      int r = (int)__popcll((unsigned long long)(m & lmask_lt));
      dg[k] = d; rk[k] = r;
      if (r == 0) hist[d * TILES + wave * TPW + k] = (uint32_t)__popcll((unsigned long long)m);
    }
    __syncthreads();                       // B2: hist counts complete
    {                                      // per-digit tile scan: wave w owns digit w
      int d = wave;
      uint32_t c0 = hist[d * TILES + lane];
      uint32_t c1 = (lane < TILES - 64) ? hist[d * TILES + 64 + lane] : 0u;
      uint32_t s0 = wave_iscan(c0, lane);
      uint32_t T0 = (uint32_t)__shfl((int)s0, 63, 64);
      uint32_t s1 = wave_iscan(c1, lane);
      uint32_t T1 = (uint32_t)__shfl((int)s1, 63, 64);
      hist[d * TILES + lane] = s0 - c0;
      if (lane < TILES - 64) hist[d * TILES + 64 + lane] = T0 + (s1 - c1);
      if (lane == 0) dtot[d] = T0 + T1;
    }
    __syncthreads();                       // B3
    if (wave == 0) {
      uint32_t x = (lane < 16) ? dtot[lane] : 0u;
      uint32_t xs = wave_iscan(x, lane);
      if (lane < 16) dbase[lane] = xs - x;
      if (lane == 0) skipf = 0u;
      if (lane < 16 && x == NS) skipf = 1u;   // single-digit pass -> identity scatter
    }
    __syncthreads();                       // B4
    if (!skipf) {
      #pragma unroll
      for (int k = 0; k < TPW; k++) {
        uint32_t dst = dbase[dg[k]] + hist[dg[k] * TILES + wave * TPW + k] + (uint32_t)rk[k];
        buf[dst] = v[k];
      }
    }
    __syncthreads();                       // B5
  }

  // ---- gather + decode epilogue ----
  for (int r = tid; r < ROWS; r += 1024) {
    if (r >= PRE_K) { boxes[r] = make_float4(0.f, 0.f, 0.f, 0.f); valid[r] = 0u; continue; }
    uint64_t kk = buf[r];
    uint32_t kd = (uint32_t)(kk >> 20);
    if (kk >= pad || kd >= 0xFF800000u) {
      boxes[r] = make_float4(0.f, 0.f, 0.f, 0.f); valid[r] = 0u; continue;
    }
    uint32_t idx = (uint32_t)(kk & 0xFFFFFu);
    float4 a = anchors[idx];
    float4 d = deltas[idx];
    float x1, y1, x2, y2; bool vv;
    decode_box(a.x, a.y, a.z, a.w, d.x, d.y, d.z, d.w, x1, y1, x2, y2, vv);
    boxes[r] = make_float4(x1, y1, x2, y2);
    valid[r] = 1u;
  }
}

// ---- K5: IoU bitmask matrix, row-major mask[row*WORDS + w] ----
__global__ void __launch_bounds__(64) k_iou(const float4* __restrict__ boxes,
                                            uint64_t* __restrict__ mask) {
  int by = blockIdx.y, bx = blockIdx.x;
  if (bx < by) return;               // only words w >= row's group are ever read
  __shared__ float4 cb[64];
  int t = threadIdx.x;
  cb[t] = boxes[bx * 64 + t];
  __syncthreads();
  int i = by * 64 + t;
  float4 b = boxes[i];
  float ax1 = b.x, ay1 = b.y, ax2 = b.z, ay2 = b.w;
  float areaA = __fmul_rn(__fsub_rn(ax2, ax1), __fsub_rn(ay2, ay1));
  uint64_t bits = 0;
  for (int c = 0; c < 64; c++) {
    float4 o = cb[c];
    float areaB = __fmul_rn(__fsub_rn(o.z, o.x), __fsub_rn(o.w, o.y));
    float ix1 = fmaxf(ax1, o.x), iy1 = fmaxf(ay1, o.y);
    float ix2 = fminf(ax2, o.z), iy2 = fminf(ay2, o.w);
    float iw = fmaxf(__fsub_rn(ix2, ix1), 0.0f);
    float ih = fmaxf(__fsub_rn(iy2, iy1), 0.0f);
    float inter = __fmul_rn(iw, ih);
    float uni = __fsub_rn(__fadd_rn(areaA, areaB), inter);
    bool sup = (uni > 0.0f) && (__fdiv_rn(inter, uni) > 0.7f);
    bits |= ((uint64_t)sup) << c;
  }
  mask[(size_t)i * WORDS + bx] = bits;
}

// wave-uniform 64-bit broadcast via v_readlane
__device__ __forceinline__ uint64_t bcast64(uint64_t v, int lane) {
  uint32_t lo = (uint32_t)__builtin_amdgcn_readlane((int)(uint32_t)v, lane);
  uint32_t hi = (uint32_t)__builtin_amdgcn_readlane((int)(uint32_t)(v >> 32), lane);
  return ((uint64_t)hi << 32) | lo;
}

#define FOLD_CHUNK 32

// ---- K6: sequential NMS scan, single wave; batched selective fold ----
// __launch_bounds__(64, 1): single wave -> unlock full VGPR budget so the
// FOLD_CHUNK load batch stays in registers with ONE vmcnt drain per chunk.
__global__ void __launch_bounds__(64, 1) k_nms(const uint64_t* __restrict__ mask,
                                               const float4* __restrict__ boxes,
                                               const uint32_t* __restrict__ valid,
                                               float* __restrict__ out) {
  __shared__ uint32_t list[1024];
  int lane = threadIdx.x;
  int w0 = lane, w1 = lane + 64;
  int w1c = (w1 < WORDS) ? w1 : 0;   // clamped safe load address
  uint64_t r0 = 0, r1 = 0;           // removed-bit words: lane owns words w0, w1
  int cnt = 0;
  uint64_t colv = mask[(size_t)lane * WORDS + 0];     // prefetch group 0
  uint32_t vf = valid[lane];
  for (int g = 0; g < WORDS; g++) {
    int base = g * 64;
    uint64_t colv_c = colv;
    uint32_t vf_c = vf;
    if (g + 1 < WORDS) {                              // prefetch group g+1
      colv = mask[(size_t)(base + 64 + lane) * WORDS + (g + 1)];
      vf = valid[base + 64 + lane];
    }
    uint64_t cur = (g < 64) ? bcast64(r0, g) : bcast64(r1, g - 64);
    uint64_t vmask = __ballot(vf_c != 0u);
    uint64_t alive = vmask & ~cur;
    uint64_t keptmask = 0;
    while (alive) {                                   // serial decision chain
      int r = __ffsll((unsigned long long)alive) - 1;
      keptmask |= 1ull << r;
      if (lane == 0) list[cnt] = (uint32_t)(base + r);
      cnt++;
      if (cnt >= POST_K) break;
      uint64_t m = bcast64(colv_c, r);                // row r's in-group word
      alive &= ~m;
      alive &= ~(1ull << r);
    }
    if (cnt >= POST_K) break;
    // ---- batched fold: chunks of FOLD_CHUNK kept rows, one vmcnt drain each ----
    uint64_t kmo = keptmask;
    uint64_t acc0 = 0, acc1 = 0;
    while (kmo) {
      uint64_t va[FOLD_CHUNK], vb[FOLD_CHUNK];
      uint32_t hasm = 0;
      uint64_t kml = kmo;
      #pragma unroll
      for (int i = 0; i < FOLD_CHUNK; i++) {          // issue all loads (independent)
        int r = (kml != 0) ? (__ffsll((unsigned long long)kml) - 1) : 0;
        hasm |= (kml != 0) ? (1u << i) : 0u;
        const uint64_t* row = mask + (size_t)(base + r) * WORDS;
        va[i] = row[w0];
        vb[i] = row[w1c];
        kml &= kml - 1;
      }
      kmo = kml;
      #pragma unroll
      for (int i = 0; i < FOLD_CHUNK; i++) {          // drain + select-OR
        uint64_t s = 0ull - (uint64_t)((hasm >> i) & 1u);
        acc0 |= va[i] & s;
        acc1 |= vb[i] & s;
      }
    }
    if (w0 > g) r0 |= acc0;
    if (w1 > g && w1 < WORDS) r1 |= acc1;
  }
  __syncthreads();
  float4* outv = (float4*)out;
  for (int k = lane; k < POST_K; k += 64)
    outv[k] = (k < cnt) ? boxes[list[k]] : make_float4(0.f, 0.f, 0.f, 0.f);
}

extern "C" void kernel_launch(void* const* d_in, const int* in_sizes, int n_in,
                              void* d_out, int out_size, void* d_ws, size_t ws_size,
                              hipStream_t stream) {
  const float4* anchors = (const float4*)d_in[1];
  const float4* deltas  = (const float4*)d_in[2];
  const float*  logits  = (const float*)d_in[3];
  char* w = (char*)d_ws;
  uint32_t* keys  = (uint32_t*)(w + OFF_KEYS);
  uint32_t* part1 = (uint32_t*)(w + OFF_PART1);
  uint32_t* part2 = (uint32_t*)(w + OFF_PART2);
  uint32_t* ctrl  = (uint32_t*)(w + OFF_CTRL);
  uint64_t* cand  = (uint64_t*)(w + OFF_CAND);
  float4*   boxes = (float4*)(w + OFF_BOXES);
  uint32_t* valid = (uint32_t*)(w + OFF_VALID);
  uint64_t* mask  = (uint64_t*)(w + OFF_MASK);
  float*    out   = (float*)d_out;

  hipMemsetAsync(w + OFF_CTRL, 0, 256, stream);   // counters only

  k_score<<<NBLK1, 1024, 0, stream>>>(anchors, deltas, logits, keys, part1, ctrl);
  k_hist2<<<NBLK1, 1024, 0, stream>>>(keys, ctrl, part2);
  k_compact<<<(N_ANCH + 255) / 256, 256, 0, stream>>>(keys, ctrl, &ctrl[0], cand);
  k_sortgather<<<1, 1024, 0, stream>>>(ctrl, cand, anchors, deltas, boxes, valid);
  k_iou<<<dim3(WORDS, WORDS), 64, 0, stream>>>(boxes, mask);
  k_nms<<<1, 64, 0, stream>>>(mask, boxes, valid, out);
}